// Round 7
// baseline (392.205 us; speedup 1.0000x reference)
//
#include <hip/hip_runtime.h>

typedef __attribute__((ext_vector_type(8))) short s16x8;
typedef __attribute__((ext_vector_type(4))) float f32x4;
typedef __attribute__((ext_vector_type(16))) float f32x16;
typedef __attribute__((ext_vector_type(4))) uint u32x4;

#define MFMA16(a, b, c) __builtin_amdgcn_mfma_f32_16x16x32_bf16((a), (b), (c), 0, 0, 0)
#define MFMA32(a, b, c) __builtin_amdgcn_mfma_f32_32x32x16_bf16((a), (b), (c), 0, 0, 0)

__device__ __forceinline__ ushort f2bf(float f) {
  uint u = __builtin_bit_cast(uint, f);
  u = (u + 0x7fffu + ((u >> 16) & 1u)) >> 16;
  return (ushort)u;
}

// ---------------- weight fp32 -> bf16 ----------------
__global__ __launch_bounds__(256) void cvt_w_kernel(
    const float* __restrict__ s0, const float* __restrict__ s1,
    const float* __restrict__ s2, const float* __restrict__ s3,
    ushort* __restrict__ d0, ushort* __restrict__ d1,
    ushort* __restrict__ d2, ushort* __restrict__ d3) {
  int i = blockIdx.x * 256 + threadIdx.x;
  const float4* s[4] = {(const float4*)s0, (const float4*)s1, (const float4*)s2, (const float4*)s3};
  ushort* d[4] = {d0, d1, d2, d3};
#pragma unroll
  for (int m = 0; m < 4; ++m) {
    float4 v = s[m][i];
    uint lo = (uint)f2bf(v.x) | ((uint)f2bf(v.y) << 16);
    uint hi = (uint)f2bf(v.z) | ((uint)f2bf(v.w) << 16);
    *(uint2*)(d[m] + (size_t)i * 4) = make_uint2(lo, hi);
  }
}

// ---------------- GroupNorm stats -> per-channel scale/shift ----------------
__global__ __launch_bounds__(256) void gn_stats_kernel(
    const float* __restrict__ x, const float* __restrict__ gw,
    const float* __restrict__ gb, float* __restrict__ scaleB,
    float* __restrict__ shiftB) {
  int b = blockIdx.x >> 3, g = blockIdx.x & 7;
  const float4* src = (const float4*)(x + ((size_t)b * 256 + g * 32) * 4096);
  float s = 0.f, ss = 0.f;
  for (int i = threadIdx.x; i < 32768; i += 256) {
    float4 v = src[i];
    s += v.x + v.y + v.z + v.w;
    ss += v.x * v.x + v.y * v.y + v.z * v.z + v.w * v.w;
  }
#pragma unroll
  for (int off = 32; off; off >>= 1) {
    s += __shfl_down(s, off);
    ss += __shfl_down(ss, off);
  }
  __shared__ float ps[4], pss[4];
  __shared__ float smu, srs;
  int w = threadIdx.x >> 6, lane = threadIdx.x & 63;
  if (lane == 0) { ps[w] = s; pss[w] = ss; }
  __syncthreads();
  if (threadIdx.x == 0) {
    float S = ps[0] + ps[1] + ps[2] + ps[3];
    float SS = pss[0] + pss[1] + pss[2] + pss[3];
    float mu = S * (1.f / 131072.f);
    float var = SS * (1.f / 131072.f) - mu * mu;
    smu = mu;
    srs = rsqrtf(var + 1e-5f);
  }
  __syncthreads();
  if (threadIdx.x < 32) {
    int ch = g * 32 + threadIdx.x;
    float sc = gw[ch] * srs;
    scaleB[b * 256 + ch] = sc;
    shiftB[b * 256 + ch] = gb[ch] - smu * sc;
  }
}

// ---------------- GN apply + transpose: x[b][c][n] -> y[b][n][c] bf16 ----------------
__global__ __launch_bounds__(256) void gn_apply_kernel(
    const float* __restrict__ x, const float* __restrict__ scaleB,
    const float* __restrict__ shiftB, ushort* __restrict__ y) {
  int bid = blockIdx.x;
  int b = bid >> 8;
  int rem = bid & 255;
  int ct = rem >> 6, nt = rem & 63;
  int t = threadIdx.x;
  __shared__ float xs[64][65];
  const float* xb = x + ((size_t)b * 256 + ct * 64) * 4096 + nt * 64;
  {
    int r = t >> 2, q = t & 3;
    const float4* src = (const float4*)(xb + (size_t)r * 4096 + q * 16);
#pragma unroll
    for (int i = 0; i < 4; ++i) {
      float4 v = src[i];
      xs[r][q * 16 + i * 4 + 0] = v.x;
      xs[r][q * 16 + i * 4 + 1] = v.y;
      xs[r][q * 16 + i * 4 + 2] = v.z;
      xs[r][q * 16 + i * 4 + 3] = v.w;
    }
  }
  __syncthreads();
  {
    int nr = t >> 2, q = t & 3;
    int c0 = q * 16;
    ushort tmp[16];
#pragma unroll
    for (int i = 0; i < 16; ++i) {
      int ch = ct * 64 + c0 + i;
      float v = xs[c0 + i][nr] * scaleB[b * 256 + ch] + shiftB[b * 256 + ch];
      tmp[i] = f2bf(v);
    }
    ushort* dst = y + ((size_t)b * 4096 + nt * 64 + nr) * 256 + ct * 64 + c0;
    uint p[8];
#pragma unroll
    for (int j = 0; j < 8; ++j) p[j] = (uint)tmp[2 * j] | ((uint)tmp[2 * j + 1] << 16);
    *(uint4*)dst = make_uint4(p[0], p[1], p[2], p[3]);
    *((uint4*)dst + 1) = make_uint4(p[4], p[5], p[6], p[7]);
  }
}

// ---------------- GEMM: C[M][N] = A[M][256] . B[N][256]^T (+bias, +resid) ----------------
template <int MODE>
__global__ __launch_bounds__(256) void gemm_bt(
    const ushort* __restrict__ A, const ushort* __restrict__ B,
    size_t aB, size_t bB, int M, int N,
    const float* __restrict__ bias, const float* __restrict__ resid,
    size_t rB, void* __restrict__ Cout, size_t cB) {
  int mTiles = M >> 7;
  int tm = blockIdx.x % mTiles, tn = blockIdx.x / mTiles;
  const ushort* Ab = A + blockIdx.y * aB + (size_t)tm * 128 * 256;
  const ushort* Bb = B + blockIdx.y * bB + (size_t)tn * 128 * 256;

  __shared__ ushort As[128 * 72];
  __shared__ ushort Bs[128 * 72];

  int t = threadIdx.x, lane = t & 63, w = t >> 6;
  int wr = w >> 1, wc = w & 1, lq = lane & 15, lg = lane >> 4;

  f32x4 acc[4][4];
#pragma unroll
  for (int i = 0; i < 4; ++i)
#pragma unroll
    for (int j = 0; j < 4; ++j) acc[i][j] = f32x4{0.f, 0.f, 0.f, 0.f};

  int srow = t >> 1, shalf = t & 1;
#pragma unroll 1
  for (int kb = 0; kb < 4; ++kb) {
    __syncthreads();
    {
      const ushort* sa = Ab + (size_t)srow * 256 + kb * 64 + shalf * 32;
      const ushort* sb = Bb + (size_t)srow * 256 + kb * 64 + shalf * 32;
      ushort* da = &As[srow * 72 + shalf * 32];
      ushort* db = &Bs[srow * 72 + shalf * 32];
#pragma unroll
      for (int j = 0; j < 4; ++j) {
        *(uint4*)(da + j * 8) = *(const uint4*)(sa + j * 8);
        *(uint4*)(db + j * 8) = *(const uint4*)(sb + j * 8);
      }
    }
    __syncthreads();
#pragma unroll
    for (int ks = 0; ks < 2; ++ks) {
      s16x8 af[4], bf[4];
#pragma unroll
      for (int mt = 0; mt < 4; ++mt)
        af[mt] = *(const s16x8*)&As[(wr * 64 + mt * 16 + lq) * 72 + ks * 32 + lg * 8];
#pragma unroll
      for (int nt = 0; nt < 4; ++nt)
        bf[nt] = *(const s16x8*)&Bs[(wc * 64 + nt * 16 + lq) * 72 + ks * 32 + lg * 8];
#pragma unroll
      for (int mt = 0; mt < 4; ++mt)
#pragma unroll
        for (int nt = 0; nt < 4; ++nt)
          acc[mt][nt] = MFMA16(af[mt], bf[nt], acc[mt][nt]);
    }
  }

  int mBase = tm * 128 + wr * 64;
  int nBase = tn * 128 + wc * 64;
#pragma unroll
  for (int mt = 0; mt < 4; ++mt) {
#pragma unroll
    for (int nt = 0; nt < 4; ++nt) {
#pragma unroll
      for (int r = 0; r < 4; ++r) {
        int row = mBase + mt * 16 + lg * 4 + r;
        int col = nBase + nt * 16 + lq;
        size_t idx = (size_t)row * N + col;
        float v = acc[mt][nt][r];
        if (MODE == 0) v += bias[col];
        else v += bias[row];
        if (MODE == 2) {
          float* C = (float*)Cout + blockIdx.y * cB;
          C[idx] = v + resid[blockIdx.y * rB + idx];
        } else {
          ushort* C = (ushort*)Cout + blockIdx.y * cB;
          C[idx] = f2bf(v);
        }
      }
    }
  }
}

// ---------------- Flash attention v5: kv-split x2, 256 q-rows/block ----------------
// Grid 256 = 8 batch x 16 qtiles x 2 kv-halves; 512 thr = 8 waves x 32 q-rows.
// Per block: stage 64 chunks (4MB) -- HALF of v4's 8MB => L3 traffic 2GB -> 1GB.
// Writes raw bf16 partials + per-row m,l; attn_merge combines the two halves.
__global__ __launch_bounds__(512, 1) void attn5_kernel(
    const ushort* __restrict__ q, const ushort* __restrict__ k,
    const ushort* __restrict__ vT, ushort* __restrict__ pb0,
    ushort* __restrict__ pb1, float* __restrict__ mlbuf) {
  const int bb = blockIdx.x & 7;          // batch -> XCD pinning
  const int rem = blockIdx.x >> 3;        // 0..31
  const int qt = rem & 15;                // 16 qtiles x 256 rows
  const int half = rem >> 4;              // kv half
  const int t = threadIdx.x, w = t >> 6, lane = t & 63;
  const int lq = lane & 31, lh = lane >> 5;

  __shared__ ushort Lf[65536];            // staging: 2 x 16384 ushorts; epilogue: 8 x 8192

  const ushort* kb = k + (size_t)bb * (4096 * 256);
  const ushort* vb = vT + (size_t)bb * (4096 * 256);

  // Q fragments (loop-invariant)
  const int qrow = bb * 4096 + qt * 256 + w * 32 + lq;
  s16x8 qf[16];
  {
    const ushort* qp = q + (size_t)qrow * 256 + lh * 8;
#pragma unroll
    for (int ct = 0; ct < 16; ++ct) qf[ct] = *(const s16x8*)(qp + ct * 16);
  }
  f32x16 oacc[8];
#pragma unroll
  for (int i = 0; i < 8; ++i) oacc[i] = (f32x16)(0.f);
  float mrun = -3e38f, lrun = 0.f;

  // stage one 32-row chunk (32KB) into buffer db; 4 gload_lds per wave
  auto stage = [&](int it, int db) {
    const int ci = half * 64 + it;
    const ushort* kcb = kb + (size_t)ci * (32 * 256);
    const ushort* vcb = vb + (size_t)ci * 32;
    ushort* base = Lf + db * 16384;
#pragma unroll
    for (int i = 0; i < 4; ++i) {
      int bu = (w * 4 + i) * 64;          // wave-uniform base unit (16B units)
      int u = bu + lane;
      if (bu < 1024) {                    // K region: row-major, unit-XOR swizzle
        int row = u >> 5, c = u & 31;
        const ushort* ksrc = kcb + row * 256 + ((c ^ (row & 7)) << 3);
        __builtin_amdgcn_global_load_lds(
            (const __attribute__((address_space(1))) uint*)ksrc,
            (__attribute__((address_space(3))) uint*)(base + bu * 8), 16, 0, 0);
      } else {                            // V region: row-pair swizzle
        int tv = u - 1024;
        int rp = tv >> 3, s8 = tv & 7;
        int x = s8 ^ (rp & 7);
        int vrow = rp * 2 + (x >> 2), uu = x & 3;
        const ushort* vsrc = vcb + (size_t)vrow * 4096 + uu * 8;
        __builtin_amdgcn_global_load_lds(
            (const __attribute__((address_space(1))) uint*)vsrc,
            (__attribute__((address_space(3))) uint*)(base + bu * 8), 16, 0, 0);
      }
    }
  };

  stage(0, 0);

#pragma unroll 1
  for (int j = 0; j < 64; ++j) {
    if (j < 63) {
      stage(j + 1, (j + 1) & 1);
      asm volatile("s_waitcnt vmcnt(4)" ::: "memory");
    } else {
      asm volatile("s_waitcnt vmcnt(0)" ::: "memory");
    }
    __builtin_amdgcn_s_barrier();

    const ushort* Kbf = Lf + (j & 1) * 16384;
    const ushort* Vbf = Kbf + 8192;

    // ---- QK^T: 16 MFMAs, 2 interleaved accumulator chains ----
    f32x16 s0 = (f32x16)(0.f), s1 = (f32x16)(0.f);
#pragma unroll
    for (int ct = 0; ct < 16; ct += 2) {
      int u0 = (ct * 2 + lh) ^ (lq & 7);
      int u1 = ((ct + 1) * 2 + lh) ^ (lq & 7);
      s16x8 kf0 = *(const s16x8*)(Kbf + lq * 256 + u0 * 8);
      s16x8 kf1 = *(const s16x8*)(Kbf + lq * 256 + u1 * 8);
      s0 = MFMA32(kf0, qf[ct], s0);
      s1 = MFMA32(kf1, qf[ct + 1], s1);
    }
    // ---- in-register online softmax ----
    float sv[16];
#pragma unroll
    for (int r = 0; r < 16; ++r) sv[r] = (s0[r] + s1[r]) * 0.0625f;
    float pmax = sv[0];
#pragma unroll
    for (int r = 1; r < 16; ++r) pmax = fmaxf(pmax, sv[r]);
    pmax = fmaxf(pmax, __shfl_xor(pmax, 32));
    if (!__all(pmax - mrun <= 8.f)) {   // defer-max (T13)
      float mnew = fmaxf(mrun, pmax);
      float alpha = __expf(mrun - mnew);
#pragma unroll
      for (int i = 0; i < 8; ++i) oacc[i] *= alpha;
      lrun *= alpha;
      mrun = mnew;
    }
    float p[16], psum = 0.f;
#pragma unroll
    for (int r = 0; r < 16; ++r) {
      p[r] = __expf(sv[r] - mrun);
      psum += p[r];
    }
    psum += __shfl_xor(psum, 32);
    lrun += psum;
    // ---- P -> PV B-frags (T12) ----
    uint c00, c01, c10, c11, c20, c21, c30, c31;
    asm("v_cvt_pk_bf16_f32 %0, %1, %2" : "=v"(c00) : "v"(p[0]),  "v"(p[1]));
    asm("v_cvt_pk_bf16_f32 %0, %1, %2" : "=v"(c01) : "v"(p[2]),  "v"(p[3]));
    asm("v_cvt_pk_bf16_f32 %0, %1, %2" : "=v"(c10) : "v"(p[4]),  "v"(p[5]));
    asm("v_cvt_pk_bf16_f32 %0, %1, %2" : "=v"(c11) : "v"(p[6]),  "v"(p[7]));
    asm("v_cvt_pk_bf16_f32 %0, %1, %2" : "=v"(c20) : "v"(p[8]),  "v"(p[9]));
    asm("v_cvt_pk_bf16_f32 %0, %1, %2" : "=v"(c21) : "v"(p[10]), "v"(p[11]));
    asm("v_cvt_pk_bf16_f32 %0, %1, %2" : "=v"(c30) : "v"(p[12]), "v"(p[13]));
    asm("v_cvt_pk_bf16_f32 %0, %1, %2" : "=v"(c31) : "v"(p[14]), "v"(p[15]));
    asm("v_permlane32_swap_b32 %0, %1" : "+v"(c00), "+v"(c10));
    asm("v_permlane32_swap_b32 %0, %1" : "+v"(c01), "+v"(c11));
    asm("v_permlane32_swap_b32 %0, %1" : "+v"(c20), "+v"(c30));
    asm("v_permlane32_swap_b32 %0, %1" : "+v"(c21), "+v"(c31));
    u32x4 t0 = {c00, c01, c10, c11};
    u32x4 t1 = {c20, c21, c30, c31};
    s16x8 pf0 = __builtin_bit_cast(s16x8, t0);
    s16x8 pf1 = __builtin_bit_cast(s16x8, t1);
    // ---- PV: A-frags from swizzled V LDS ----
    const int rp7 = (lq >> 1) & 7;
    const int b4 = (lq & 1) * 4;
#pragma unroll
    for (int db = 0; db < 8; ++db) {
      const ushort* base = Vbf + (db * 16 + (lq >> 1)) * 64;
      int sl0 = (b4 + lh) ^ rp7;
      int sl1 = (b4 + 2 + lh) ^ rp7;
      s16x8 vf0 = *(const s16x8*)(base + sl0 * 8);
      s16x8 vf1 = *(const s16x8*)(base + sl1 * 8);
      oacc[db] = MFMA32(vf0, pf0, oacc[db]);
      oacc[db] = MFMA32(vf1, pf1, oacc[db]);
    }
    asm volatile("" ::: "memory");
    __builtin_amdgcn_s_barrier();
    asm volatile("" ::: "memory");
  }

  // ---- epilogue: raw partials -> LDS transpose -> coalesced global store ----
  {
    ushort* wreg = Lf + w * 8192;         // 32 q-rows x 256 d per wave
#pragma unroll
    for (int db = 0; db < 8; ++db)
#pragma unroll
      for (int rp = 0; rp < 8; ++rp) {
        int r0 = rp * 2;
        int d0 = db * 32 + (r0 & 3) + 8 * (r0 >> 2) + 4 * lh;
        uint pk;
        asm("v_cvt_pk_bf16_f32 %0, %1, %2"
            : "=v"(pk) : "v"(oacc[db][r0]), "v"(oacc[db][r0 + 1]));
        *(uint*)&wreg[lq * 256 + d0] = pk;
      }
    if (lh == 0) {
      int idx = half * 32768 + bb * 4096 + qt * 256 + w * 32 + lq;
      mlbuf[idx] = mrun;
      mlbuf[65536 + idx] = lrun;
    }
  }
  __syncthreads();
  {
    int r = t >> 1;                        // 0..255 row in tile
    const ushort* srcr = Lf + (r >> 5) * 8192 + (r & 31) * 256 + (t & 1) * 128;
    ushort* pbase = half ? pb1 : pb0;
    ushort* dstr = pbase + ((size_t)bb * 4096 + qt * 256 + r) * 256 + (t & 1) * 128;
#pragma unroll
    for (int jj = 0; jj < 16; ++jj)
      ((uint4*)dstr)[jj] = ((const uint4*)srcr)[jj];
  }
}

// ---------------- merge the two kv-half partials ----------------
__global__ __launch_bounds__(256) void attn_merge_kernel(
    const ushort* __restrict__ pb0, const ushort* __restrict__ pb1,
    const float* __restrict__ mlbuf, ushort* __restrict__ o) {
  int gr = blockIdx.x * 8 + (threadIdx.x >> 5);   // global row 0..32767
  int dq = threadIdx.x & 31;                      // 8 d-elems each
  float m0 = mlbuf[gr], m1 = mlbuf[32768 + gr];
  float l0 = mlbuf[65536 + gr], l1 = mlbuf[65536 + 32768 + gr];
  float M = fmaxf(m0, m1);
  float e0 = __expf(m0 - M), e1 = __expf(m1 - M);
  float inv = 1.f / (l0 * e0 + l1 * e1);
  float w0 = e0 * inv, w1 = e1 * inv;
  const size_t off = (size_t)gr * 256 + dq * 8;
  u32x4 a = *(const u32x4*)(pb0 + off);
  u32x4 b = *(const u32x4*)(pb1 + off);
  uint outw[4];
#pragma unroll
  for (int i = 0; i < 4; ++i) {
    float alo = __builtin_bit_cast(float, a[i] << 16);
    float ahi = __builtin_bit_cast(float, a[i] & 0xffff0000u);
    float blo = __builtin_bit_cast(float, b[i] << 16);
    float bhi = __builtin_bit_cast(float, b[i] & 0xffff0000u);
    float flo = alo * w0 + blo * w1;
    float fhi = ahi * w0 + bhi * w1;
    asm("v_cvt_pk_bf16_f32 %0, %1, %2" : "=v"(outw[i]) : "v"(flo), "v"(fhi));
  }
  u32x4 ov = {outw[0], outw[1], outw[2], outw[3]};
  *(u32x4*)(o + off) = ov;
}

extern "C" void kernel_launch(void* const* d_in, const int* in_sizes, int n_in,
                              void* d_out, int out_size, void* d_ws, size_t ws_size,
                              hipStream_t stream) {
  const float* x   = (const float*)d_in[0];
  const float* gnw = (const float*)d_in[1];
  const float* gnb = (const float*)d_in[2];
  const float* wq  = (const float*)d_in[3];
  const float* bq  = (const float*)d_in[4];
  const float* wk  = (const float*)d_in[5];
  const float* bk  = (const float*)d_in[6];
  const float* wv  = (const float*)d_in[7];
  const float* bv  = (const float*)d_in[8];
  const float* wp  = (const float*)d_in[9];
  const float* bp  = (const float*)d_in[10];

  const size_t SEQ = 4096, CH = 256;
  const size_t MAT = SEQ * CH;
  char* ws = (char*)d_ws;
  const size_t BUF = 8 * MAT * 2;        // 16 MiB
  ushort* y    = (ushort*)(ws + 0 * BUF);
  ushort* qb   = (ushort*)(ws + 1 * BUF);
  ushort* kb_  = (ushort*)(ws + 2 * BUF);
  ushort* vtb  = (ushort*)(ws + 3 * BUF);
  ushort* pb1  = (ushort*)(ws + 4 * BUF);
  ushort* pb0  = y;                      // y dead after V GEMM
  ushort* oab  = qb;                     // q dead after attn; merge writes here
  ushort* wqb  = (ushort*)(ws + 5 * BUF);
  ushort* wkb  = wqb + 65536;
  ushort* wvb  = wkb + 65536;
  ushort* wpb  = wvb + 65536;
  float* scaleB = (float*)(wpb + 65536);
  float* shiftB = scaleB + 8 * 256;
  float* mlbuf  = (float*)d_out;         // 512KB scratch; overwritten by proj GEMM

  cvt_w_kernel<<<64, 256, 0, stream>>>(wq, wk, wv, wp, wqb, wkb, wvb, wpb);
  gn_stats_kernel<<<64, 256, 0, stream>>>(x, gnw, gnb, scaleB, shiftB);
  gn_apply_kernel<<<2048, 256, 0, stream>>>(x, scaleB, shiftB, y);

  gemm_bt<0><<<dim3(64, 8), 256, 0, stream>>>(y, wqb, MAT, 0, 4096, 256, bq,
                                              nullptr, 0, qb, MAT);
  gemm_bt<0><<<dim3(64, 8), 256, 0, stream>>>(y, wkb, MAT, 0, 4096, 256, bk,
                                              nullptr, 0, kb_, MAT);
  gemm_bt<1><<<dim3(64, 8), 256, 0, stream>>>(wvb, y, 0, MAT, 256, 4096, bv,
                                              nullptr, 0, vtb, MAT);

  attn5_kernel<<<256, 512, 0, stream>>>(qb, kb_, vtb, pb0, pb1, mlbuf);
  attn_merge_kernel<<<4096, 256, 0, stream>>>(pb0, pb1, mlbuf, oab);

  gemm_bt<2><<<dim3(64, 8), 256, 0, stream>>>(wpb, oab, 0, MAT, 256, 4096, bp,
                                              x, MAT, d_out, MAT);
}

// Round 8
// 375.142 us; speedup vs baseline: 1.0455x; 1.0455x over previous
//
#include <hip/hip_runtime.h>

typedef __attribute__((ext_vector_type(8))) short s16x8;
typedef __attribute__((ext_vector_type(4))) float f32x4;
typedef __attribute__((ext_vector_type(16))) float f32x16;
typedef __attribute__((ext_vector_type(4))) uint u32x4;

#define MFMA16(a, b, c) __builtin_amdgcn_mfma_f32_16x16x32_bf16((a), (b), (c), 0, 0, 0)
#define MFMA32(a, b, c) __builtin_amdgcn_mfma_f32_32x32x16_bf16((a), (b), (c), 0, 0, 0)

__device__ __forceinline__ ushort f2bf(float f) {
  uint u = __builtin_bit_cast(uint, f);
  u = (u + 0x7fffu + ((u >> 16) & 1u)) >> 16;
  return (ushort)u;
}

// ---------------- weight fp32 -> bf16 ----------------
__global__ __launch_bounds__(256) void cvt_w_kernel(
    const float* __restrict__ s0, const float* __restrict__ s1,
    const float* __restrict__ s2, const float* __restrict__ s3,
    ushort* __restrict__ d0, ushort* __restrict__ d1,
    ushort* __restrict__ d2, ushort* __restrict__ d3) {
  int i = blockIdx.x * 256 + threadIdx.x;
  const float4* s[4] = {(const float4*)s0, (const float4*)s1, (const float4*)s2, (const float4*)s3};
  ushort* d[4] = {d0, d1, d2, d3};
#pragma unroll
  for (int m = 0; m < 4; ++m) {
    float4 v = s[m][i];
    uint lo = (uint)f2bf(v.x) | ((uint)f2bf(v.y) << 16);
    uint hi = (uint)f2bf(v.z) | ((uint)f2bf(v.w) << 16);
    *(uint2*)(d[m] + (size_t)i * 4) = make_uint2(lo, hi);
  }
}

// ---------------- GroupNorm stats -> per-channel scale/shift ----------------
__global__ __launch_bounds__(256) void gn_stats_kernel(
    const float* __restrict__ x, const float* __restrict__ gw,
    const float* __restrict__ gb, float* __restrict__ scaleB,
    float* __restrict__ shiftB) {
  int b = blockIdx.x >> 3, g = blockIdx.x & 7;
  const float4* src = (const float4*)(x + ((size_t)b * 256 + g * 32) * 4096);
  float s = 0.f, ss = 0.f;
  for (int i = threadIdx.x; i < 32768; i += 256) {
    float4 v = src[i];
    s += v.x + v.y + v.z + v.w;
    ss += v.x * v.x + v.y * v.y + v.z * v.z + v.w * v.w;
  }
#pragma unroll
  for (int off = 32; off; off >>= 1) {
    s += __shfl_down(s, off);
    ss += __shfl_down(ss, off);
  }
  __shared__ float ps[4], pss[4];
  __shared__ float smu, srs;
  int w = threadIdx.x >> 6, lane = threadIdx.x & 63;
  if (lane == 0) { ps[w] = s; pss[w] = ss; }
  __syncthreads();
  if (threadIdx.x == 0) {
    float S = ps[0] + ps[1] + ps[2] + ps[3];
    float SS = pss[0] + pss[1] + pss[2] + pss[3];
    float mu = S * (1.f / 131072.f);
    float var = SS * (1.f / 131072.f) - mu * mu;
    smu = mu;
    srs = rsqrtf(var + 1e-5f);
  }
  __syncthreads();
  if (threadIdx.x < 32) {
    int ch = g * 32 + threadIdx.x;
    float sc = gw[ch] * srs;
    scaleB[b * 256 + ch] = sc;
    shiftB[b * 256 + ch] = gb[ch] - smu * sc;
  }
}

// ---------------- GN apply + transpose: x[b][c][n] -> y[b][n][c] bf16 ----------------
__global__ __launch_bounds__(256) void gn_apply_kernel(
    const float* __restrict__ x, const float* __restrict__ scaleB,
    const float* __restrict__ shiftB, ushort* __restrict__ y) {
  int bid = blockIdx.x;
  int b = bid >> 8;
  int rem = bid & 255;
  int ct = rem >> 6, nt = rem & 63;
  int t = threadIdx.x;
  __shared__ float xs[64][65];
  const float* xb = x + ((size_t)b * 256 + ct * 64) * 4096 + nt * 64;
  {
    int r = t >> 2, q = t & 3;
    const float4* src = (const float4*)(xb + (size_t)r * 4096 + q * 16);
#pragma unroll
    for (int i = 0; i < 4; ++i) {
      float4 v = src[i];
      xs[r][q * 16 + i * 4 + 0] = v.x;
      xs[r][q * 16 + i * 4 + 1] = v.y;
      xs[r][q * 16 + i * 4 + 2] = v.z;
      xs[r][q * 16 + i * 4 + 3] = v.w;
    }
  }
  __syncthreads();
  {
    int nr = t >> 2, q = t & 3;
    int c0 = q * 16;
    ushort tmp[16];
#pragma unroll
    for (int i = 0; i < 16; ++i) {
      int ch = ct * 64 + c0 + i;
      float v = xs[c0 + i][nr] * scaleB[b * 256 + ch] + shiftB[b * 256 + ch];
      tmp[i] = f2bf(v);
    }
    ushort* dst = y + ((size_t)b * 4096 + nt * 64 + nr) * 256 + ct * 64 + c0;
    uint p[8];
#pragma unroll
    for (int j = 0; j < 8; ++j) p[j] = (uint)tmp[2 * j] | ((uint)tmp[2 * j + 1] << 16);
    *(uint4*)dst = make_uint4(p[0], p[1], p[2], p[3]);
    *((uint4*)dst + 1) = make_uint4(p[4], p[5], p[6], p[7]);
  }
}

// ---------------- GEMM: C[M][N] = A[M][256] . B[N][256]^T (+bias, +resid) ----------------
template <int MODE>
__global__ __launch_bounds__(256) void gemm_bt(
    const ushort* __restrict__ A, const ushort* __restrict__ B,
    size_t aB, size_t bB, int M, int N,
    const float* __restrict__ bias, const float* __restrict__ resid,
    size_t rB, void* __restrict__ Cout, size_t cB) {
  int mTiles = M >> 7;
  int tm = blockIdx.x % mTiles, tn = blockIdx.x / mTiles;
  const ushort* Ab = A + blockIdx.y * aB + (size_t)tm * 128 * 256;
  const ushort* Bb = B + blockIdx.y * bB + (size_t)tn * 128 * 256;

  __shared__ ushort As[128 * 72];
  __shared__ ushort Bs[128 * 72];

  int t = threadIdx.x, lane = t & 63, w = t >> 6;
  int wr = w >> 1, wc = w & 1, lq = lane & 15, lg = lane >> 4;

  f32x4 acc[4][4];
#pragma unroll
  for (int i = 0; i < 4; ++i)
#pragma unroll
    for (int j = 0; j < 4; ++j) acc[i][j] = f32x4{0.f, 0.f, 0.f, 0.f};

  int srow = t >> 1, shalf = t & 1;
#pragma unroll 1
  for (int kb = 0; kb < 4; ++kb) {
    __syncthreads();
    {
      const ushort* sa = Ab + (size_t)srow * 256 + kb * 64 + shalf * 32;
      const ushort* sb = Bb + (size_t)srow * 256 + kb * 64 + shalf * 32;
      ushort* da = &As[srow * 72 + shalf * 32];
      ushort* db = &Bs[srow * 72 + shalf * 32];
#pragma unroll
      for (int j = 0; j < 4; ++j) {
        *(uint4*)(da + j * 8) = *(const uint4*)(sa + j * 8);
        *(uint4*)(db + j * 8) = *(const uint4*)(sb + j * 8);
      }
    }
    __syncthreads();
#pragma unroll
    for (int ks = 0; ks < 2; ++ks) {
      s16x8 af[4], bf[4];
#pragma unroll
      for (int mt = 0; mt < 4; ++mt)
        af[mt] = *(const s16x8*)&As[(wr * 64 + mt * 16 + lq) * 72 + ks * 32 + lg * 8];
#pragma unroll
      for (int nt = 0; nt < 4; ++nt)
        bf[nt] = *(const s16x8*)&Bs[(wc * 64 + nt * 16 + lq) * 72 + ks * 32 + lg * 8];
#pragma unroll
      for (int mt = 0; mt < 4; ++mt)
#pragma unroll
        for (int nt = 0; nt < 4; ++nt)
          acc[mt][nt] = MFMA16(af[mt], bf[nt], acc[mt][nt]);
    }
  }

  int mBase = tm * 128 + wr * 64;
  int nBase = tn * 128 + wc * 64;
#pragma unroll
  for (int mt = 0; mt < 4; ++mt) {
#pragma unroll
    for (int nt = 0; nt < 4; ++nt) {
#pragma unroll
      for (int r = 0; r < 4; ++r) {
        int row = mBase + mt * 16 + lg * 4 + r;
        int col = nBase + nt * 16 + lq;
        size_t idx = (size_t)row * N + col;
        float v = acc[mt][nt][r];
        if (MODE == 0) v += bias[col];
        else v += bias[row];
        if (MODE == 2) {
          float* C = (float*)Cout + blockIdx.y * cB;
          C[idx] = v + resid[blockIdx.y * rB + idx];
        } else {
          ushort* C = (ushort*)Cout + blockIdx.y * cB;
          C[idx] = f2bf(v);
        }
      }
    }
  }
}

// ---------------- Flash attention v6: kv-split x2 + within-wave pipeline ----------------
// Grid 256 = 8 batch x 16 qtiles x 2 kv-halves; 512 thr = 8 waves x 32 q-rows.
// Pipelined: per iter j, QK(j) + PV(j-1) form one MFMA cluster (setprio'd),
// softmax(j) at the end. V staged one iter behind K; drain PV(63) post-loop.
__global__ __launch_bounds__(512, 1) void attn6_kernel(
    const ushort* __restrict__ q, const ushort* __restrict__ k,
    const ushort* __restrict__ vT, ushort* __restrict__ pb0,
    ushort* __restrict__ pb1, float* __restrict__ mlbuf) {
  const int bb = blockIdx.x & 7;          // batch -> XCD pinning
  const int rem = blockIdx.x >> 3;        // 0..31
  const int qt = rem & 15;                // 16 qtiles x 256 rows
  const int half = rem >> 4;              // kv half
  const int t = threadIdx.x, w = t >> 6, lane = t & 63;
  const int lq = lane & 31, lh = lane >> 5;

  // main loop: K buffers [0,16384), V buffers [16384,32768); epilogue: 8x8192
  __shared__ ushort Lf[65536];

  const ushort* kb = k + (size_t)bb * (4096 * 256);
  const ushort* vb = vT + (size_t)bb * (4096 * 256);

  // Q fragments (loop-invariant)
  const int qrow = bb * 4096 + qt * 256 + w * 32 + lq;
  s16x8 qf[16];
  {
    const ushort* qp = q + (size_t)qrow * 256 + lh * 8;
#pragma unroll
    for (int ct = 0; ct < 16; ++ct) qf[ct] = *(const s16x8*)(qp + ct * 16);
  }
  f32x16 oacc[8];
#pragma unroll
  for (int i = 0; i < 8; ++i) oacc[i] = (f32x16)(0.f);
  float mrun = -3e38f, lrun = 0.f;
  s16x8 pf0 = (s16x8)(short)0, pf1 = (s16x8)(short)0;

  // waves 0-3 stage K(chunk) -> kbuf[db]; waves 4-7 stage V(chunk) -> vbuf[db]
  auto stageK = [&](int ck, int db) {
    const ushort* kcb = kb + (size_t)(half * 64 + ck) * (32 * 256);
    ushort* base = Lf + db * 8192;
#pragma unroll
    for (int i = 0; i < 4; ++i) {
      int bu = (w * 4 + i) * 64;
      int u = bu + lane;
      int row = u >> 5, c = u & 31;
      const ushort* ksrc = kcb + row * 256 + ((c ^ (row & 7)) << 3);
      __builtin_amdgcn_global_load_lds(
          (const __attribute__((address_space(1))) uint*)ksrc,
          (__attribute__((address_space(3))) uint*)(base + bu * 8), 16, 0, 0);
    }
  };
  auto stageV = [&](int cv, int db) {
    const ushort* vcb = vb + (size_t)(half * 64 + cv) * 32;
    ushort* base = Lf + 16384 + db * 8192;
#pragma unroll
    for (int i = 0; i < 4; ++i) {
      int bu = ((w - 4) * 4 + i) * 64;
      int u = bu + lane;
      int rp = u >> 3, s8 = u & 7;
      int x = s8 ^ (rp & 7);
      int vrow = rp * 2 + (x >> 2), uu = x & 3;
      const ushort* vsrc = vcb + (size_t)vrow * 4096 + uu * 8;
      __builtin_amdgcn_global_load_lds(
          (const __attribute__((address_space(1))) uint*)vsrc,
          (__attribute__((address_space(3))) uint*)(base + bu * 8), 16, 0, 0);
    }
  };

  if (w < 4) stageK(0, 0);

  const int rp7 = (lq >> 1) & 7;
  const int b4 = (lq & 1) * 4;

#pragma unroll 1
  for (int j = 0; j < 64; ++j) {
    if (w < 4) {
      if (j < 63) stageK(j + 1, (j + 1) & 1);
    } else {
      stageV(j, j & 1);
    }
    if (j < 63) {
      asm volatile("s_waitcnt vmcnt(4)" ::: "memory");
    } else {
      asm volatile("s_waitcnt vmcnt(0)" ::: "memory");
    }
    __builtin_amdgcn_s_barrier();

    // ---- MFMA cluster: QK(j) + PV(j-1), one interleavable region ----
    __builtin_amdgcn_s_setprio(1);
    const ushort* Kbf = Lf + (j & 1) * 8192;
    f32x16 s0 = (f32x16)(0.f), s1 = (f32x16)(0.f);
#pragma unroll
    for (int ct = 0; ct < 16; ct += 2) {
      int u0 = (ct * 2 + lh) ^ (lq & 7);
      int u1 = ((ct + 1) * 2 + lh) ^ (lq & 7);
      s16x8 kf0 = *(const s16x8*)(Kbf + lq * 256 + u0 * 8);
      s16x8 kf1 = *(const s16x8*)(Kbf + lq * 256 + u1 * 8);
      s0 = MFMA32(kf0, qf[ct], s0);
      s1 = MFMA32(kf1, qf[ct + 1], s1);
    }
    if (j > 0) {
      const ushort* Vbf = Lf + 16384 + ((j - 1) & 1) * 8192;
#pragma unroll
      for (int db = 0; db < 8; ++db) {
        const ushort* base = Vbf + (db * 16 + (lq >> 1)) * 64;
        int sl0 = (b4 + lh) ^ rp7;
        int sl1 = (b4 + 2 + lh) ^ rp7;
        s16x8 vf0 = *(const s16x8*)(base + sl0 * 8);
        s16x8 vf1 = *(const s16x8*)(base + sl1 * 8);
        oacc[db] = MFMA32(vf0, pf0, oacc[db]);
        oacc[db] = MFMA32(vf1, pf1, oacc[db]);
      }
    }
    __builtin_amdgcn_s_setprio(0);

    // ---- softmax(j): rescale-after-PV(j-1) keeps online algebra exact ----
    float sv[16];
#pragma unroll
    for (int r = 0; r < 16; ++r) sv[r] = (s0[r] + s1[r]) * 0.0625f;
    float pmax = sv[0];
#pragma unroll
    for (int r = 1; r < 16; ++r) pmax = fmaxf(pmax, sv[r]);
    pmax = fmaxf(pmax, __shfl_xor(pmax, 32));
    if (!__all(pmax - mrun <= 8.f)) {   // defer-max (T13)
      float mnew = fmaxf(mrun, pmax);
      float alpha = __expf(mrun - mnew);
#pragma unroll
      for (int i = 0; i < 8; ++i) oacc[i] *= alpha;
      lrun *= alpha;
      mrun = mnew;
    }
    float p[16], psum = 0.f;
#pragma unroll
    for (int r = 0; r < 16; ++r) {
      p[r] = __expf(sv[r] - mrun);
      psum += p[r];
    }
    psum += __shfl_xor(psum, 32);
    lrun += psum;
    // ---- P -> PV B-frags (T12) for NEXT iteration ----
    uint c00, c01, c10, c11, c20, c21, c30, c31;
    asm("v_cvt_pk_bf16_f32 %0, %1, %2" : "=v"(c00) : "v"(p[0]),  "v"(p[1]));
    asm("v_cvt_pk_bf16_f32 %0, %1, %2" : "=v"(c01) : "v"(p[2]),  "v"(p[3]));
    asm("v_cvt_pk_bf16_f32 %0, %1, %2" : "=v"(c10) : "v"(p[4]),  "v"(p[5]));
    asm("v_cvt_pk_bf16_f32 %0, %1, %2" : "=v"(c11) : "v"(p[6]),  "v"(p[7]));
    asm("v_cvt_pk_bf16_f32 %0, %1, %2" : "=v"(c20) : "v"(p[8]),  "v"(p[9]));
    asm("v_cvt_pk_bf16_f32 %0, %1, %2" : "=v"(c21) : "v"(p[10]), "v"(p[11]));
    asm("v_cvt_pk_bf16_f32 %0, %1, %2" : "=v"(c30) : "v"(p[12]), "v"(p[13]));
    asm("v_cvt_pk_bf16_f32 %0, %1, %2" : "=v"(c31) : "v"(p[14]), "v"(p[15]));
    asm("v_permlane32_swap_b32 %0, %1" : "+v"(c00), "+v"(c10));
    asm("v_permlane32_swap_b32 %0, %1" : "+v"(c01), "+v"(c11));
    asm("v_permlane32_swap_b32 %0, %1" : "+v"(c20), "+v"(c30));
    asm("v_permlane32_swap_b32 %0, %1" : "+v"(c21), "+v"(c31));
    u32x4 t0 = {c00, c01, c10, c11};
    u32x4 t1 = {c20, c21, c30, c31};
    pf0 = __builtin_bit_cast(s16x8, t0);
    pf1 = __builtin_bit_cast(s16x8, t1);

    asm volatile("" ::: "memory");
    __builtin_amdgcn_s_barrier();
    asm volatile("" ::: "memory");
  }

  // ---- drain PV(63) (V(63) in vbuf[1], completion ensured by vmcnt(0)+barrier) ----
  {
    const ushort* Vbf = Lf + 16384 + 8192;
#pragma unroll
    for (int db = 0; db < 8; ++db) {
      const ushort* base = Vbf + (db * 16 + (lq >> 1)) * 64;
      int sl0 = (b4 + lh) ^ rp7;
      int sl1 = (b4 + 2 + lh) ^ rp7;
      s16x8 vf0 = *(const s16x8*)(base + sl0 * 8);
      s16x8 vf1 = *(const s16x8*)(base + sl1 * 8);
      oacc[db] = MFMA32(vf0, pf0, oacc[db]);
      oacc[db] = MFMA32(vf1, pf1, oacc[db]);
    }
  }
  __syncthreads();   // all waves done reading K/V buffers before epilogue overwrites

  // ---- epilogue: raw partials -> LDS transpose (XOR-swz) -> coalesced store ----
  {
    uint* wregu = (uint*)Lf + w * 4096;   // 32 q-rows x 128 uints per wave
#pragma unroll
    for (int db = 0; db < 8; ++db)
#pragma unroll
      for (int rp = 0; rp < 8; ++rp) {
        int r0 = rp * 2;
        int d0 = db * 32 + (r0 & 3) + 8 * (r0 >> 2) + 4 * lh;
        uint pk;
        asm("v_cvt_pk_bf16_f32 %0, %1, %2"
            : "=v"(pk) : "v"(oacc[db][r0]), "v"(oacc[db][r0 + 1]));
        int idx = lq * 128 + (d0 >> 1);
        wregu[idx ^ ((lq & 7) << 2)] = pk;
      }
    if (lh == 0) {
      int idx = half * 32768 + bb * 4096 + qt * 256 + w * 32 + lq;
      mlbuf[idx] = mrun;
      mlbuf[65536 + idx] = lrun;
    }
  }
  __syncthreads();
  {
    int r = t >> 1;                        // 0..255 row in tile
    int wv2 = r >> 5, lqr = r & 31;
    const uint* basep = (const uint*)Lf + wv2 * 4096;
    ushort* pbase = half ? pb1 : pb0;
    ushort* dstr = pbase + ((size_t)bb * 4096 + qt * 256 + r) * 256 + (t & 1) * 128;
#pragma unroll
    for (int jj = 0; jj < 16; ++jj) {
      int ui = lqr * 128 + (t & 1) * 64 + jj * 4;
      u32x4 v = *(const u32x4*)(basep + (ui ^ ((lqr & 7) << 2)));
      *(u32x4*)(dstr + jj * 8) = v;
    }
  }
}

// ---------------- merge the two kv-half partials ----------------
__global__ __launch_bounds__(256) void attn_merge_kernel(
    const ushort* __restrict__ pb0, const ushort* __restrict__ pb1,
    const float* __restrict__ mlbuf, ushort* __restrict__ o) {
  int gr = blockIdx.x * 8 + (threadIdx.x >> 5);   // global row 0..32767
  int dq = threadIdx.x & 31;                      // 8 d-elems each
  float m0 = mlbuf[gr], m1 = mlbuf[32768 + gr];
  float l0 = mlbuf[65536 + gr], l1 = mlbuf[65536 + 32768 + gr];
  float M = fmaxf(m0, m1);
  float e0 = __expf(m0 - M), e1 = __expf(m1 - M);
  float inv = 1.f / (l0 * e0 + l1 * e1);
  float w0 = e0 * inv, w1 = e1 * inv;
  const size_t off = (size_t)gr * 256 + dq * 8;
  u32x4 a = *(const u32x4*)(pb0 + off);
  u32x4 b = *(const u32x4*)(pb1 + off);
  uint outw[4];
#pragma unroll
  for (int i = 0; i < 4; ++i) {
    float alo = __builtin_bit_cast(float, a[i] << 16);
    float ahi = __builtin_bit_cast(float, a[i] & 0xffff0000u);
    float blo = __builtin_bit_cast(float, b[i] << 16);
    float bhi = __builtin_bit_cast(float, b[i] & 0xffff0000u);
    float flo = alo * w0 + blo * w1;
    float fhi = ahi * w0 + bhi * w1;
    asm("v_cvt_pk_bf16_f32 %0, %1, %2" : "=v"(outw[i]) : "v"(flo), "v"(fhi));
  }
  u32x4 ov = {outw[0], outw[1], outw[2], outw[3]};
  *(u32x4*)(o + off) = ov;
}

extern "C" void kernel_launch(void* const* d_in, const int* in_sizes, int n_in,
                              void* d_out, int out_size, void* d_ws, size_t ws_size,
                              hipStream_t stream) {
  const float* x   = (const float*)d_in[0];
  const float* gnw = (const float*)d_in[1];
  const float* gnb = (const float*)d_in[2];
  const float* wq  = (const float*)d_in[3];
  const float* bq  = (const float*)d_in[4];
  const float* wk  = (const float*)d_in[5];
  const float* bk  = (const float*)d_in[6];
  const float* wv  = (const float*)d_in[7];
  const float* bv  = (const float*)d_in[8];
  const float* wp  = (const float*)d_in[9];
  const float* bp  = (const float*)d_in[10];

  const size_t SEQ = 4096, CH = 256;
  const size_t MAT = SEQ * CH;
  char* ws = (char*)d_ws;
  const size_t BUF = 8 * MAT * 2;        // 16 MiB
  ushort* y    = (ushort*)(ws + 0 * BUF);
  ushort* qb   = (ushort*)(ws + 1 * BUF);
  ushort* kb_  = (ushort*)(ws + 2 * BUF);
  ushort* vtb  = (ushort*)(ws + 3 * BUF);
  ushort* pb1  = (ushort*)(ws + 4 * BUF);
  ushort* pb0  = y;                      // y dead after V GEMM
  ushort* oab  = qb;                     // q dead after attn; merge writes here
  ushort* wqb  = (ushort*)(ws + 5 * BUF);
  ushort* wkb  = wqb + 65536;
  ushort* wvb  = wkb + 65536;
  ushort* wpb  = wvb + 65536;
  float* scaleB = (float*)(wpb + 65536);
  float* shiftB = scaleB + 8 * 256;
  float* mlbuf  = (float*)d_out;         // 512KB scratch; overwritten by proj GEMM

  cvt_w_kernel<<<64, 256, 0, stream>>>(wq, wk, wv, wp, wqb, wkb, wvb, wpb);
  gn_stats_kernel<<<64, 256, 0, stream>>>(x, gnw, gnb, scaleB, shiftB);
  gn_apply_kernel<<<2048, 256, 0, stream>>>(x, scaleB, shiftB, y);

  gemm_bt<0><<<dim3(64, 8), 256, 0, stream>>>(y, wqb, MAT, 0, 4096, 256, bq,
                                              nullptr, 0, qb, MAT);
  gemm_bt<0><<<dim3(64, 8), 256, 0, stream>>>(y, wkb, MAT, 0, 4096, 256, bk,
                                              nullptr, 0, kb_, MAT);
  gemm_bt<1><<<dim3(64, 8), 256, 0, stream>>>(wvb, y, 0, MAT, 256, 4096, bv,
                                              nullptr, 0, vtb, MAT);

  attn6_kernel<<<256, 512, 0, stream>>>(qb, kb_, vtb, pb0, pb1, mlbuf);
  attn_merge_kernel<<<4096, 256, 0, stream>>>(pb0, pb1, mlbuf, oab);

  gemm_bt<2><<<dim3(64, 8), 256, 0, stream>>>(wpb, oab, 0, MAT, 256, 4096, bp,
                                              x, MAT, d_out, MAT);
}